// Round 1
// baseline (2428.555 us; speedup 1.0000x reference)
//
#include <hip/hip_runtime.h>
#include <hip/hip_bf16.h>

// Shapes (fixed): T=4, B=16, C=256 (gate/filt each), O=2C=512 conv-out, L=2048.
// TAU=1.2, VTH=0.5. Spikes are exactly (v >= 0.5) in forward.
// z = sigmoid(gate)*tanh(filt) with gate,filt in {0,1} -> z in {0, Z01, Z11}.

#define T_STEPS 4
#define BB 16
#define C_CH 256
#define O_CH 512
#define LL 2048
#define TL 64      // l-tile per block
#define OUT_HALF 33554432  // T*B*C*L

// ---------------- Kernel A: embedding MLP -> proj -> pk[b][o][k] ----------------
// pk[b][o][k] = sum_c proj[b][c] * w_conv[o][c][k]   (+ b_conv[o] folded into k==1)
__global__ __launch_bounds__(256) void embed_proj_kernel(
    const int* __restrict__ dstep,
    const float* __restrict__ w_emb1, const float* __restrict__ b_emb1,
    const float* __restrict__ w_emb2, const float* __restrict__ b_emb2,
    const float* __restrict__ w_proj, const float* __restrict__ b_proj,
    const float* __restrict__ w_conv, const float* __restrict__ b_conv,
    float* __restrict__ pk)
{
    const int b = blockIdx.x;
    const int tid = threadIdx.x;
    __shared__ float h[256], emb[256], proj[256];
    const float ds = (float)dstep[b];
    {
        float t1 = ds * w_emb1[tid] + b_emb1[tid];
        float sg = 1.0f / (1.0f + expf(-t1));
        h[tid] = t1 * sg;               // silu
    }
    __syncthreads();
    {
        float s = b_emb2[tid];
        const float* wrow = w_emb2 + tid * 256;
        for (int c = 0; c < 256; ++c) s += h[c] * wrow[c];
        emb[tid] = s;
    }
    __syncthreads();
    {
        float s = b_proj[tid];
        const float* wrow = w_proj + tid * 256;
        for (int c = 0; c < 256; ++c) s += emb[c] * wrow[c];
        proj[tid] = s;
    }
    __syncthreads();
    for (int i = tid; i < 512 * 3; i += 256) {
        int o = i / 3, k = i - o * 3;
        float s = (k == 1) ? b_conv[o] : 0.0f;
        const float* wrow = w_conv + (size_t)o * 768 + k;
        for (int c = 0; c < 256; ++c) s += proj[c] * wrow[c * 3];
        pk[(size_t)b * 1536 + i] = s;
    }
}

// ---------------- Kernel B: conv (C->2C, 3-tap) + LIF + z ----------------
// Block: 64 conv-out channels (32 gate/filt PAIRS) x TL=64 l positions, loops t=0..3.
// Thread: 4 (paired) channels x 4 l. LIF state v[16] lives in registers across t.
// Channel map for oo = og*4+j: ch = g0 + 2*og + (j&1) + ((j&2)?256:0)
//   -> j=0,1 are gate channels pg,pg+1; j=2,3 are the matching filt channels.
__global__ __launch_bounds__(256) void conv_lif_kernel(
    const float* __restrict__ x,
    const float* __restrict__ w_conv,
    const float* __restrict__ pk,
    __hip_bfloat16* __restrict__ zbuf)
{
    const int lb = blockIdx.x;   // 0..31
    const int ob = blockIdx.y;   // 0..7
    const int b  = blockIdx.z;   // 0..15
    const int l0 = lb * TL;
    const int g0 = ob * 32;      // pair base (gate channel base)
    const int tid = threadIdx.x;
    const int lg = tid & 15;     // l-group: l = l0 + lg*4 + lj
    const int og = tid >> 4;     // 0..15: channel quad oo = og*4+j

    __shared__ float xs[32 * 68];        // x chunk: 32 c-rows x 66 (stride 68, col0 = l0-1)
    __shared__ float wsh[32 * 3 * 64];   // W chunk: [ck=cl*3+k][oo]
    __shared__ float pksh[64 * 3];

    if (tid < 192) {
        int oo = tid / 3, k = tid - oo * 3;
        int j = oo & 3, ogg = oo >> 2;
        int ch = g0 + 2 * ogg + (j & 1) + ((j & 2) ? 256 : 0);
        pksh[oo * 3 + k] = pk[(size_t)b * 1536 + ch * 3 + k];
    }

    float v[16];
#pragma unroll
    for (int i = 0; i < 16; ++i) v[i] = 0.0f;

    // W loader mapping: thread -> (oo = tid>>2, sub = tid&3), 24 contiguous floats each
    const int w_oo = tid >> 2;
    const int w_sub = tid & 3;
    const int w_j = w_oo & 3, w_og = w_oo >> 2;
    const int w_ch = g0 + 2 * w_og + (w_j & 1) + ((w_j & 2) ? 256 : 0);

    const float Z01 = 0.3807970780f;   // sigmoid(0)*tanh(1)
    const float Z11 = 0.5567699413f;   // sigmoid(1)*tanh(1)

    for (int t = 0; t < T_STEPS; ++t) {
        float acc[16];
#pragma unroll
        for (int i = 0; i < 16; ++i) acc[i] = 0.0f;

        for (int cc = 0; cc < 8; ++cc) {
            __syncthreads();   // protect LDS from previous iteration's readers
            // x chunk: rows c = cc*32..+31, cols l0-1 .. l0+64 (66 values)
            {
                const float* xb = x + ((size_t)(t * BB + b) * C_CH + cc * 32) * LL;
                for (int i = tid; i < 32 * 66; i += 256) {
                    int cl = i / 66;
                    int li = i - cl * 66;
                    int l = l0 - 1 + li;
                    float val = (l >= 0 && l < LL) ? xb[(size_t)cl * LL + l] : 0.0f;
                    xs[cl * 68 + li] = val;
                }
            }
            // W chunk: wsh[(cl*3+k)*64 + oo]
            {
                const float* wb = w_conv + (size_t)w_ch * 768 + cc * 96 + w_sub * 24;
#pragma unroll
                for (int m6 = 0; m6 < 6; ++m6) {
                    float4 w4 = *(const float4*)(wb + m6 * 4);
                    int ck = w_sub * 24 + m6 * 4;
                    wsh[(ck + 0) * 64 + w_oo] = w4.x;
                    wsh[(ck + 1) * 64 + w_oo] = w4.y;
                    wsh[(ck + 2) * 64 + w_oo] = w4.z;
                    wsh[(ck + 3) * 64 + w_oo] = w4.w;
                }
            }
            __syncthreads();
            // accumulate: per c-row, sliding 6-wide x window covers k=0..2, lj=0..3
            for (int cl = 0; cl < 32; ++cl) {
                float xw[6];
                float4 xa = *(const float4*)&xs[cl * 68 + lg * 4];
                float2 xb2 = *(const float2*)&xs[cl * 68 + lg * 4 + 4];
                xw[0] = xa.x; xw[1] = xa.y; xw[2] = xa.z; xw[3] = xa.w;
                xw[4] = xb2.x; xw[5] = xb2.y;
#pragma unroll
                for (int k = 0; k < 3; ++k) {
                    float4 w4 = *(const float4*)&wsh[(cl * 3 + k) * 64 + og * 4];
                    float wv[4] = { w4.x, w4.y, w4.z, w4.w };
#pragma unroll
                    for (int j = 0; j < 4; ++j)
#pragma unroll
                        for (int lj = 0; lj < 4; ++lj)
                            acc[j * 4 + lj] += wv[j] * xw[lj + k];
                }
            }
        }

        // LIF update + spikes
        float sp[16];
#pragma unroll
        for (int j = 0; j < 4; ++j) {
            int oo = og * 4 + j;
            float p0 = pksh[oo * 3 + 0];
            float p1 = pksh[oo * 3 + 1];   // includes b_conv
            float p2 = pksh[oo * 3 + 2];
#pragma unroll
            for (int lj = 0; lj < 4; ++lj) {
                int l = l0 + lg * 4 + lj;
                float y2 = acc[j * 4 + lj] + p1
                         + (l > 0 ? p0 : 0.0f)
                         + (l < LL - 1 ? p2 : 0.0f);
                float vv = v[j * 4 + lj];
                vv = vv + (y2 - vv) / 1.2f;           // exact division like reference
                float s = (vv >= 0.5f) ? 1.0f : 0.0f; // heaviside forward value
                sp[j * 4 + lj] = s;
                v[j * 4 + lj] = vv * (1.0f - s);
            }
        }

        // z = f(gate spike, filt spike), write bf16
#pragma unroll
        for (int p = 0; p < 2; ++p) {
            union { __hip_bfloat16 h[4]; uint2 u; } packv;
#pragma unroll
            for (int lj = 0; lj < 4; ++lj) {
                float g = sp[p * 4 + lj];
                float f = sp[(2 + p) * 4 + lj];
                float z = (f != 0.0f) ? ((g != 0.0f) ? Z11 : Z01) : 0.0f;
                packv.h[lj] = __float2bfloat16(z);
            }
            int ch = g0 + 2 * og + p;
            size_t zi = ((size_t)(t * BB + b) * C_CH + ch) * LL + l0 + lg * 4;
            *(uint2*)((char*)zbuf + zi * 2) = packv.u;
        }
    }
}

// ---------------- Kernel C: res/skip GEMMs + bias + x add ----------------
// Block: 64 o x 64 l for one (t,b). Thread: 4o x 4l, two accumulators (res, skip).
__global__ __launch_bounds__(256) void out_gemm_kernel(
    const float* __restrict__ x,
    const __hip_bfloat16* __restrict__ zbuf,
    const float* __restrict__ w_skip, const float* __restrict__ b_skip,
    const float* __restrict__ w_res,  const float* __restrict__ b_res,
    float* __restrict__ out)
{
    const int lb  = blockIdx.x;  // 0..31
    const int obk = blockIdx.y;  // 0..3
    const int tb  = blockIdx.z;  // 0..63 = t*16+b
    const int l0 = lb * 64, o0 = obk * 64;
    const int tid = threadIdx.x;
    const int lg = tid & 15, og = tid >> 4;

    __shared__ float zsh[32 * 68];
    __shared__ float wrh[32 * 68];
    __shared__ float wkh[32 * 68];

    float accR[16], accS[16];
#pragma unroll
    for (int i = 0; i < 16; ++i) { accR[i] = 0.0f; accS[i] = 0.0f; }

    for (int cc = 0; cc < 8; ++cc) {
        __syncthreads();
        {
            const __hip_bfloat16* zb = zbuf + ((size_t)tb * C_CH + cc * 32) * LL + l0;
            for (int i = tid; i < 32 * 64; i += 256) {
                int cl = i >> 6, li = i & 63;
                zsh[cl * 68 + li] = __bfloat162float(zb[(size_t)cl * LL + li]);
            }
            for (int i = tid; i < 2048; i += 256) {
                int oo = i >> 5, cl = i & 31;
                int c = cc * 32 + cl;
                wrh[cl * 68 + oo] = w_res[(size_t)(o0 + oo) * 256 + c];
                wkh[cl * 68 + oo] = w_skip[(size_t)(o0 + oo) * 256 + c];
            }
        }
        __syncthreads();
        for (int cl = 0; cl < 32; ++cl) {
            float4 z4 = *(const float4*)&zsh[cl * 68 + lg * 4];
            float4 r4 = *(const float4*)&wrh[cl * 68 + og * 4];
            float4 k4 = *(const float4*)&wkh[cl * 68 + og * 4];
            float zz[4] = { z4.x, z4.y, z4.z, z4.w };
            float rr[4] = { r4.x, r4.y, r4.z, r4.w };
            float kk[4] = { k4.x, k4.y, k4.z, k4.w };
#pragma unroll
            for (int j = 0; j < 4; ++j)
#pragma unroll
                for (int lj = 0; lj < 4; ++lj) {
                    accR[j * 4 + lj] += rr[j] * zz[lj];
                    accS[j * 4 + lj] += kk[j] * zz[lj];
                }
        }
    }

    const size_t base = (size_t)tb * C_CH * LL;
#pragma unroll
    for (int j = 0; j < 4; ++j) {
        int o = o0 + og * 4 + j;
        float br = b_res[o], bs = b_skip[o];
        size_t idx = base + (size_t)o * LL + l0 + lg * 4;
        float4 x4 = *(const float4*)&x[idx];
        float4 ro, so;
        ro.x = x4.x + accR[j * 4 + 0] + br;
        ro.y = x4.y + accR[j * 4 + 1] + br;
        ro.z = x4.z + accR[j * 4 + 2] + br;
        ro.w = x4.w + accR[j * 4 + 3] + br;
        so.x = accS[j * 4 + 0] + bs;
        so.y = accS[j * 4 + 1] + bs;
        so.z = accS[j * 4 + 2] + bs;
        so.w = accS[j * 4 + 3] + bs;
        *(float4*)&out[idx] = ro;
        *(float4*)&out[OUT_HALF + idx] = so;
    }
}

extern "C" void kernel_launch(void* const* d_in, const int* in_sizes, int n_in,
                              void* d_out, int out_size, void* d_ws, size_t ws_size,
                              hipStream_t stream) {
    const float* x       = (const float*)d_in[0];
    const int*   dstep   = (const int*)d_in[1];
    const float* w_emb1  = (const float*)d_in[2];
    const float* b_emb1  = (const float*)d_in[3];
    const float* w_emb2  = (const float*)d_in[4];
    const float* b_emb2  = (const float*)d_in[5];
    const float* w_proj  = (const float*)d_in[6];
    const float* b_proj  = (const float*)d_in[7];
    const float* w_conv  = (const float*)d_in[8];
    const float* b_conv  = (const float*)d_in[9];
    const float* w_skip  = (const float*)d_in[10];
    const float* b_skip  = (const float*)d_in[11];
    const float* w_res   = (const float*)d_in[12];
    const float* b_res   = (const float*)d_in[13];
    float* out = (float*)d_out;

    // ws layout: pk floats [16][512][3] at 0 (96 KiB), zbuf bf16 [4][16][256][2048] at 128 KiB
    float* pk = (float*)d_ws;
    __hip_bfloat16* zbuf = (__hip_bfloat16*)((char*)d_ws + 131072);

    embed_proj_kernel<<<BB, 256, 0, stream>>>(dstep, w_emb1, b_emb1, w_emb2, b_emb2,
                                              w_proj, b_proj, w_conv, b_conv, pk);
    conv_lif_kernel<<<dim3(LL / TL, 8, BB), 256, 0, stream>>>(x, w_conv, pk, zbuf);
    out_gemm_kernel<<<dim3(LL / 64, C_CH / 64, T_STEPS * BB), 256, 0, stream>>>(
        x, zbuf, w_skip, b_skip, w_res, b_res, out);
}

// Round 2
// 2357.452 us; speedup vs baseline: 1.0302x; 1.0302x over previous
//
#include <hip/hip_runtime.h>
#include <hip/hip_bf16.h>

// Shapes (fixed): T=4, B=16, C=256 (gate/filt each), O=2C=512 conv-out, L=2048.
// TAU=1.2, VTH=0.5. Spikes are exactly (v >= 0.5) in forward.
// z = sigmoid(gate)*tanh(filt) with gate,filt in {0,1} -> z in {0, Z01, Z11}.

#define T_STEPS 4
#define BB 16
#define C_CH 256
#define O_CH 512
#define LL 2048
#define OUT_HALF 33554432  // T*B*C*L

// ---------------- Kernel A: embedding MLP -> proj -> pk[b][o][k] ----------------
__global__ __launch_bounds__(256) void embed_proj_kernel(
    const int* __restrict__ dstep,
    const float* __restrict__ w_emb1, const float* __restrict__ b_emb1,
    const float* __restrict__ w_emb2, const float* __restrict__ b_emb2,
    const float* __restrict__ w_proj, const float* __restrict__ b_proj,
    const float* __restrict__ w_conv, const float* __restrict__ b_conv,
    float* __restrict__ pk)
{
    const int b = blockIdx.x;
    const int tid = threadIdx.x;
    __shared__ float h[256], emb[256], proj[256];
    const float ds = (float)dstep[b];
    {
        float t1 = ds * w_emb1[tid] + b_emb1[tid];
        float sg = 1.0f / (1.0f + expf(-t1));
        h[tid] = t1 * sg;               // silu
    }
    __syncthreads();
    {
        float s = b_emb2[tid];
        const float* wrow = w_emb2 + tid * 256;
        for (int c = 0; c < 256; ++c) s += h[c] * wrow[c];
        emb[tid] = s;
    }
    __syncthreads();
    {
        float s = b_proj[tid];
        const float* wrow = w_proj + tid * 256;
        for (int c = 0; c < 256; ++c) s += emb[c] * wrow[c];
        proj[tid] = s;
    }
    __syncthreads();
    for (int i = tid; i < 512 * 3; i += 256) {
        int o = i / 3, k = i - o * 3;
        float s = (k == 1) ? b_conv[o] : 0.0f;
        const float* wrow = w_conv + (size_t)o * 768 + k;
        for (int c = 0; c < 256; ++c) s += proj[c] * wrow[c * 3];
        pk[(size_t)b * 1536 + i] = s;
    }
}

// ---------------- Kernel B: conv (C->2C, 3-tap) + LIF + z ----------------
// Block: 64 conv-out channels (32 gate/filt PAIRS) x 128 l positions, loops t=0..3.
// Thread: 4 paired channels x 8 l (two 4-l groups 64 apart -> 2-way-free LDS reads).
// Channel map for oo = og*4+j: ch = g0 + 2*og + (j&1) + ((j&2)?256:0)
__global__ __launch_bounds__(256) void conv_lif_kernel(
    const float* __restrict__ x,
    const float* __restrict__ w_conv,
    const float* __restrict__ pk,
    __hip_bfloat16* __restrict__ zbuf)
{
    const int lb = blockIdx.x;   // 0..15
    const int ob = blockIdx.y;   // 0..7
    const int b  = blockIdx.z;   // 0..15
    const int l0 = lb * 128;
    const int g0 = ob * 32;      // pair base (gate channel base)
    const int tid = threadIdx.x;
    const int lg = tid & 15;     // l-group: l = l0 + g*64 + lg*4 + lj
    const int og = tid >> 4;     // 0..15: channel quad oo = og*4+j

    __shared__ float xs[32 * 132];       // x chunk: 32 c-rows x 130 (stride 132, col0 = l0-1)
    __shared__ float wsh[32 * 3 * 64];   // W chunk: [ck=cl*3+k][oo]
    __shared__ float pksh[64 * 3];

    if (tid < 192) {
        int oo = tid / 3, k = tid - oo * 3;
        int j = oo & 3, ogg = oo >> 2;
        int ch = g0 + 2 * ogg + (j & 1) + ((j & 2) ? 256 : 0);
        pksh[oo * 3 + k] = pk[(size_t)b * 1536 + ch * 3 + k];
    }

    float v[32];
#pragma unroll
    for (int i = 0; i < 32; ++i) v[i] = 0.0f;

    // W loader mapping: thread -> (oo = tid>>2, sub = tid&3), 24 contiguous floats each
    const int w_oo = tid >> 2;
    const int w_sub = tid & 3;
    const int w_j = w_oo & 3, w_og = w_oo >> 2;
    const int w_ch = g0 + 2 * w_og + (w_j & 1) + ((w_j & 2) ? 256 : 0);

    const float Z01 = 0.3807970780f;   // sigmoid(0)*tanh(1)
    const float Z11 = 0.5567699413f;   // sigmoid(1)*tanh(1)

    for (int t = 0; t < T_STEPS; ++t) {
        float acc[32];
#pragma unroll
        for (int i = 0; i < 32; ++i) acc[i] = 0.0f;

        for (int cc = 0; cc < 8; ++cc) {
            __syncthreads();   // protect LDS from previous iteration's readers
            // x chunk: rows c = cc*32..+31, cols l0-1 .. l0+128 (130 values)
            {
                const float* xb = x + ((size_t)(t * BB + b) * C_CH + cc * 32) * LL;
                for (int i = tid; i < 32 * 130; i += 256) {
                    int cl = i / 130;
                    int li = i - cl * 130;
                    int l = l0 - 1 + li;
                    float val = (l >= 0 && l < LL) ? xb[(size_t)cl * LL + l] : 0.0f;
                    xs[cl * 132 + li] = val;
                }
            }
            // W chunk: wsh[(cl*3+k)*64 + oo]
            {
                const float* wb = w_conv + (size_t)w_ch * 768 + cc * 96 + w_sub * 24;
#pragma unroll
                for (int m6 = 0; m6 < 6; ++m6) {
                    float4 w4 = *(const float4*)(wb + m6 * 4);
                    int ck = w_sub * 24 + m6 * 4;
                    wsh[(ck + 0) * 64 + w_oo] = w4.x;
                    wsh[(ck + 1) * 64 + w_oo] = w4.y;
                    wsh[(ck + 2) * 64 + w_oo] = w4.z;
                    wsh[(ck + 3) * 64 + w_oo] = w4.w;
                }
            }
            __syncthreads();
            // accumulate: per c-row, two sliding 6-wide x windows cover k=0..2, lj=0..3
            for (int cl = 0; cl < 32; ++cl) {
                float xw0[6], xw1[6];
                {
                    float4 xa = *(const float4*)&xs[cl * 132 + lg * 4];
                    float2 xb2 = *(const float2*)&xs[cl * 132 + lg * 4 + 4];
                    xw0[0] = xa.x; xw0[1] = xa.y; xw0[2] = xa.z; xw0[3] = xa.w;
                    xw0[4] = xb2.x; xw0[5] = xb2.y;
                }
                {
                    float4 xa = *(const float4*)&xs[cl * 132 + 64 + lg * 4];
                    float2 xb2 = *(const float2*)&xs[cl * 132 + 64 + lg * 4 + 4];
                    xw1[0] = xa.x; xw1[1] = xa.y; xw1[2] = xa.z; xw1[3] = xa.w;
                    xw1[4] = xb2.x; xw1[5] = xb2.y;
                }
#pragma unroll
                for (int k = 0; k < 3; ++k) {
                    float4 w4 = *(const float4*)&wsh[(cl * 3 + k) * 64 + og * 4];
                    float wv[4] = { w4.x, w4.y, w4.z, w4.w };
#pragma unroll
                    for (int j = 0; j < 4; ++j) {
#pragma unroll
                        for (int lj = 0; lj < 4; ++lj) {
                            acc[j * 4 + lj]      += wv[j] * xw0[lj + k];
                            acc[16 + j * 4 + lj] += wv[j] * xw1[lj + k];
                        }
                    }
                }
            }
        }

        // LIF update + spikes
        float sp[32];
#pragma unroll
        for (int g = 0; g < 2; ++g) {
#pragma unroll
            for (int j = 0; j < 4; ++j) {
                int oo = og * 4 + j;
                float p0 = pksh[oo * 3 + 0];
                float p1 = pksh[oo * 3 + 1];   // includes b_conv
                float p2 = pksh[oo * 3 + 2];
#pragma unroll
                for (int lj = 0; lj < 4; ++lj) {
                    int l = l0 + g * 64 + lg * 4 + lj;
                    float y2 = acc[g * 16 + j * 4 + lj] + p1
                             + (l > 0 ? p0 : 0.0f)
                             + (l < LL - 1 ? p2 : 0.0f);
                    float vv = v[g * 16 + j * 4 + lj];
                    vv = vv + (y2 - vv) / 1.2f;           // exact division like reference
                    float s = (vv >= 0.5f) ? 1.0f : 0.0f; // heaviside forward value
                    sp[g * 16 + j * 4 + lj] = s;
                    v[g * 16 + j * 4 + lj] = vv * (1.0f - s);
                }
            }
        }

        // z = f(gate spike, filt spike), write bf16
#pragma unroll
        for (int g = 0; g < 2; ++g) {
#pragma unroll
            for (int p = 0; p < 2; ++p) {
                union { __hip_bfloat16 h[4]; uint2 u; } packv;
#pragma unroll
                for (int lj = 0; lj < 4; ++lj) {
                    float gg = sp[g * 16 + p * 4 + lj];
                    float ff = sp[g * 16 + (2 + p) * 4 + lj];
                    float z = (ff != 0.0f) ? ((gg != 0.0f) ? Z11 : Z01) : 0.0f;
                    packv.h[lj] = __float2bfloat16(z);
                }
                int ch = g0 + 2 * og + p;
                size_t zi = ((size_t)(t * BB + b) * C_CH + ch) * LL + l0 + g * 64 + lg * 4;
                *(uint2*)((char*)zbuf + zi * 2) = packv.u;
            }
        }
    }
}

// ---------------- Kernel C: res/skip GEMMs + bias + x add ----------------
// Block: 64 o x 128 l for one (t,b). Thread: 4o x 8l (two 4-l groups), dual acc.
__global__ __launch_bounds__(256) void out_gemm_kernel(
    const float* __restrict__ x,
    const __hip_bfloat16* __restrict__ zbuf,
    const float* __restrict__ w_skip, const float* __restrict__ b_skip,
    const float* __restrict__ w_res,  const float* __restrict__ b_res,
    float* __restrict__ out)
{
    const int lb  = blockIdx.x;  // 0..15
    const int obk = blockIdx.y;  // 0..3
    const int tb  = blockIdx.z;  // 0..63 = t*16+b
    const int l0 = lb * 128, o0 = obk * 64;
    const int tid = threadIdx.x;
    const int lg = tid & 15, og = tid >> 4;

    __shared__ float zsh[32 * 132];
    __shared__ float wrh[32 * 68];
    __shared__ float wkh[32 * 68];

    float accR[32], accS[32];
#pragma unroll
    for (int i = 0; i < 32; ++i) { accR[i] = 0.0f; accS[i] = 0.0f; }

    // z staging map: row = tid>>3 (0..31), colg = tid&7 -> 16 contiguous bf16
    const int z_row = tid >> 3;
    const int z_colg = tid & 7;

    for (int cc = 0; cc < 8; ++cc) {
        __syncthreads();
        {
            const __hip_bfloat16* zb = zbuf + ((size_t)tb * C_CH + cc * 32 + z_row) * LL
                                     + l0 + z_colg * 16;
#pragma unroll
            for (int half = 0; half < 2; ++half) {
                uint4 raw = *(const uint4*)((const char*)zb + half * 16);
                const unsigned int w[4] = { raw.x, raw.y, raw.z, raw.w };
                float f[8];
#pragma unroll
                for (int q = 0; q < 4; ++q) {
                    union { float fv; unsigned int uv; } lo, hi;
                    lo.uv = (w[q] & 0xFFFFu) << 16;
                    hi.uv = (w[q] & 0xFFFF0000u);
                    f[q * 2 + 0] = lo.fv;
                    f[q * 2 + 1] = hi.fv;
                }
                float4* dst = (float4*)&zsh[z_row * 132 + z_colg * 16 + half * 8];
                dst[0] = make_float4(f[0], f[1], f[2], f[3]);
                dst[1] = make_float4(f[4], f[5], f[6], f[7]);
            }
            for (int i = tid; i < 2048; i += 256) {
                int oo = i >> 5, cl = i & 31;
                int c = cc * 32 + cl;
                wrh[cl * 68 + oo] = w_res[(size_t)(o0 + oo) * 256 + c];
                wkh[cl * 68 + oo] = w_skip[(size_t)(o0 + oo) * 256 + c];
            }
        }
        __syncthreads();
        for (int cl = 0; cl < 32; ++cl) {
            float4 z0 = *(const float4*)&zsh[cl * 132 + lg * 4];
            float4 z1 = *(const float4*)&zsh[cl * 132 + 64 + lg * 4];
            float4 r4 = *(const float4*)&wrh[cl * 68 + og * 4];
            float4 k4 = *(const float4*)&wkh[cl * 68 + og * 4];
            float zz0[4] = { z0.x, z0.y, z0.z, z0.w };
            float zz1[4] = { z1.x, z1.y, z1.z, z1.w };
            float rr[4] = { r4.x, r4.y, r4.z, r4.w };
            float kk[4] = { k4.x, k4.y, k4.z, k4.w };
#pragma unroll
            for (int j = 0; j < 4; ++j) {
#pragma unroll
                for (int lj = 0; lj < 4; ++lj) {
                    accR[j * 4 + lj]      += rr[j] * zz0[lj];
                    accS[j * 4 + lj]      += kk[j] * zz0[lj];
                    accR[16 + j * 4 + lj] += rr[j] * zz1[lj];
                    accS[16 + j * 4 + lj] += kk[j] * zz1[lj];
                }
            }
        }
    }

    const size_t base = (size_t)tb * C_CH * LL;
#pragma unroll
    for (int g = 0; g < 2; ++g) {
#pragma unroll
        for (int j = 0; j < 4; ++j) {
            int o = o0 + og * 4 + j;
            float br = b_res[o], bs = b_skip[o];
            size_t idx = base + (size_t)o * LL + l0 + g * 64 + lg * 4;
            float4 x4 = *(const float4*)&x[idx];
            float4 ro, so;
            ro.x = x4.x + accR[g * 16 + j * 4 + 0] + br;
            ro.y = x4.y + accR[g * 16 + j * 4 + 1] + br;
            ro.z = x4.z + accR[g * 16 + j * 4 + 2] + br;
            ro.w = x4.w + accR[g * 16 + j * 4 + 3] + br;
            so.x = accS[g * 16 + j * 4 + 0] + bs;
            so.y = accS[g * 16 + j * 4 + 1] + bs;
            so.z = accS[g * 16 + j * 4 + 2] + bs;
            so.w = accS[g * 16 + j * 4 + 3] + bs;
            *(float4*)&out[idx] = ro;
            *(float4*)&out[OUT_HALF + idx] = so;
        }
    }
}

extern "C" void kernel_launch(void* const* d_in, const int* in_sizes, int n_in,
                              void* d_out, int out_size, void* d_ws, size_t ws_size,
                              hipStream_t stream) {
    const float* x       = (const float*)d_in[0];
    const int*   dstep   = (const int*)d_in[1];
    const float* w_emb1  = (const float*)d_in[2];
    const float* b_emb1  = (const float*)d_in[3];
    const float* w_emb2  = (const float*)d_in[4];
    const float* b_emb2  = (const float*)d_in[5];
    const float* w_proj  = (const float*)d_in[6];
    const float* b_proj  = (const float*)d_in[7];
    const float* w_conv  = (const float*)d_in[8];
    const float* b_conv  = (const float*)d_in[9];
    const float* w_skip  = (const float*)d_in[10];
    const float* b_skip  = (const float*)d_in[11];
    const float* w_res   = (const float*)d_in[12];
    const float* b_res   = (const float*)d_in[13];
    float* out = (float*)d_out;

    // ws layout: pk floats [16][512][3] at 0 (96 KiB), zbuf bf16 [4][16][256][2048] at 128 KiB
    float* pk = (float*)d_ws;
    __hip_bfloat16* zbuf = (__hip_bfloat16*)((char*)d_ws + 131072);

    embed_proj_kernel<<<BB, 256, 0, stream>>>(dstep, w_emb1, b_emb1, w_emb2, b_emb2,
                                              w_proj, b_proj, w_conv, b_conv, pk);
    conv_lif_kernel<<<dim3(LL / 128, 8, BB), 256, 0, stream>>>(x, w_conv, pk, zbuf);
    out_gemm_kernel<<<dim3(LL / 128, C_CH / 64, T_STEPS * BB), 256, 0, stream>>>(
        x, zbuf, w_skip, b_skip, w_res, b_res, out);
}